// Round 5
// baseline (1946.959 us; speedup 1.0000x reference)
//
#include <hip/hip_runtime.h>
#include <hip/hip_fp16.h>

#define NN 50000
#define NE 800000
#define NL 12
#define DD 64

__device__ __forceinline__ float rl(float v, int k) {
    return __int_as_float(__builtin_amdgcn_readlane(__float_as_int(v), k));
}

// ---------------------------------------------------------------------------
// Detect whether edge_index is stored as int64 (odd 32-bit words all zero).
// ---------------------------------------------------------------------------
__global__ __launch_bounds__(256) void detect_i64(const unsigned int* __restrict__ w,
                                                  int* __restrict__ flag) {
    __shared__ unsigned int red[256];
    unsigned int v = 0;
    for (int i = threadIdx.x; i < 4096; i += 256) v |= w[2 * i + 1];
    red[threadIdx.x] = v;
    __syncthreads();
    for (int s = 128; s > 0; s >>= 1) {
        if (threadIdx.x < s) red[threadIdx.x] |= red[threadIdx.x + s];
        __syncthreads();
    }
    if (threadIdx.x == 0) *flag = (red[0] == 0u) ? 1 : 0;
}

__global__ __launch_bounds__(256) void hist_k(const void* __restrict__ eidx,
                                              const int* __restrict__ flag,
                                              int* __restrict__ cnt) {
    int e = blockIdx.x * 256 + threadIdx.x;
    if (e >= NE) return;
    int dst;
    if (*flag) dst = (int)((const long long*)eidx)[NE + e];
    else       dst = ((const int*)eidx)[NE + e];
    atomicAdd(&cnt[dst], 1);
}

__global__ __launch_bounds__(1024) void scan_k(const int* __restrict__ cnt,
                                               int* __restrict__ offs,
                                               int* __restrict__ cursor) {
    __shared__ int wsum[16];
    __shared__ int carry_s;
    int tid = threadIdx.x;
    int lane = tid & 63;
    int wv = tid >> 6;
    if (tid == 0) carry_s = 0;
    __syncthreads();
    for (int base = 0; base < NN; base += 1024) {
        int i = base + tid;
        int v = (i < NN) ? cnt[i] : 0;
        int incl = v;
        #pragma unroll
        for (int d = 1; d < 64; d <<= 1) {
            int t = __shfl_up(incl, d);
            if (lane >= d) incl += t;
        }
        if (lane == 63) wsum[wv] = incl;
        __syncthreads();
        if (wv == 0) {
            int s = (lane < 16) ? wsum[lane] : 0;
            #pragma unroll
            for (int d = 1; d < 16; d <<= 1) {
                int t = __shfl_up(s, d);
                if (lane >= d) s += t;
            }
            if (lane < 16) wsum[lane] = s;
        }
        __syncthreads();
        int wbase = (wv == 0) ? 0 : wsum[wv - 1];
        int carry = carry_s;
        int excl = carry + wbase + incl - v;
        if (i < NN) { offs[i] = excl; cursor[i] = excl; }
        __syncthreads();
        if (tid == 1023) carry_s = carry + wsum[15];
        __syncthreads();
    }
    if (threadIdx.x == 0) offs[NN] = carry_s;
}

__global__ __launch_bounds__(256) void fill_k(const void* __restrict__ eidx,
                                              const float* __restrict__ ew,
                                              const int* __restrict__ flag,
                                              int* __restrict__ cursor,
                                              int2* __restrict__ csr) {
    int e = blockIdx.x * 256 + threadIdx.x;
    if (e >= NE) return;
    int src, dst;
    if (*flag) {
        const long long* p = (const long long*)eidx;
        src = (int)p[e];
        dst = (int)p[NE + e];
    } else {
        const int* p = (const int*)eidx;
        src = p[e];
        dst = p[NE + e];
    }
    int pos = atomicAdd(&cursor[dst], 1);
    csr[pos] = make_int2(src, __float_as_int(ew[e]));
}

// ---------------------------------------------------------------------------
// One-shot fp32 -> fp16 conversion of x0 (gather shadow copy).
// ---------------------------------------------------------------------------
__global__ __launch_bounds__(256) void cvt_k(const float* __restrict__ x,
                                             __half* __restrict__ y) {
    int i = blockIdx.x * 256 + threadIdx.x;      // indexes float4 groups
    if (i >= NN * DD / 4) return;
    float4 v = ((const float4*)x)[i];
    __half2 a = __floats2half2_rn(v.x, v.y);
    __half2 b = __floats2half2_rn(v.z, v.w);
    ((__half2*)y)[2 * i]     = a;
    ((__half2*)y)[2 * i + 1] = b;
}

// ---------------------------------------------------------------------------
// Fused layer, R3 structure, gather path switched to fp16 shadow rows:
// row = 128B (2 lines) instead of 256B (4 lines) -> halves TCC fill traffic,
// and per-XCD src working set (6.4 MB) nearly fits the 4 MiB L2.
// Epilogue writes fp32 xout AND fp16 xout16 for the next layer's gather.
// ---------------------------------------------------------------------------
__global__ __launch_bounds__(512) void layer_k(const float* __restrict__ xin,
                                               const __half* __restrict__ xin16,
                                               const float* __restrict__ Wl,
                                               const float* __restrict__ bl,
                                               const int* __restrict__ offs,
                                               const int2* __restrict__ csr,
                                               float* __restrict__ xout,
                                               __half* __restrict__ xout16) {
    __shared__ float Ws[128 * 64];
    int tid = threadIdx.x;
    const float4* Wv = (const float4*)Wl;
    float4* Wsv = (float4*)Ws;
    #pragma unroll
    for (int i = 0; i < 4; ++i) Wsv[tid + 512 * i] = Wv[tid + 512 * i];
    __syncthreads();

    int wave = tid >> 6;
    int lane = tid & 63;
    int nbase = blockIdx.x * 32 + wave * 4;

    int n0 = min(nbase + 0, NN - 1);
    int n1 = min(nbase + 1, NN - 1);
    int n2 = min(nbase + 2, NN - 1);
    int n3 = min(nbase + 3, NN - 1);

    float xl0 = xin[(size_t)n0 * DD + lane];
    float xl1 = xin[(size_t)n1 * DD + lane];
    float xl2 = xin[(size_t)n2 * DD + lane];
    float xl3 = xin[(size_t)n3 * DD + lane];
    float bias = bl[lane];

    int a0 = offs[n0], a1 = offs[n0 + 1];
    int b0 = offs[n1], b1 = offs[n1 + 1];
    int c0 = offs[n2], c1 = offs[n2 + 1];
    int d0 = offs[n3], d1 = offs[n3 + 1];
    int mx = max(max(a1 - a0, b1 - b0), max(c1 - c0, d1 - d0));

    float acc0 = 0.f, acc1 = 0.f, acc2 = 0.f, acc3 = 0.f;
    for (int base = 0; base < mx; base += 8) {
        float w0[8], w1[8], w2[8], w3[8];
        __half v0[8], v1[8], v2[8], v3[8];
        #pragma unroll
        for (int j = 0; j < 8; ++j) {
            int e;
            int2 sw;
            e = a0 + base + j;
            sw = csr[(e < a1) ? e : a0];
            w0[j] = (e < a1) ? __int_as_float(sw.y) : 0.f;
            v0[j] = xin16[(size_t)sw.x * DD + lane];
            e = b0 + base + j;
            sw = csr[(e < b1) ? e : b0];
            w1[j] = (e < b1) ? __int_as_float(sw.y) : 0.f;
            v1[j] = xin16[(size_t)sw.x * DD + lane];
            e = c0 + base + j;
            sw = csr[(e < c1) ? e : c0];
            w2[j] = (e < c1) ? __int_as_float(sw.y) : 0.f;
            v2[j] = xin16[(size_t)sw.x * DD + lane];
            e = d0 + base + j;
            sw = csr[(e < d1) ? e : d0];
            w3[j] = (e < d1) ? __int_as_float(sw.y) : 0.f;
            v3[j] = xin16[(size_t)sw.x * DD + lane];
        }
        #pragma unroll
        for (int j = 0; j < 8; ++j) {
            acc0 += w0[j] * __half2float(v0[j]);
            acc1 += w1[j] * __half2float(v1[j]);
            acc2 += w2[j] * __half2float(v2[j]);
            acc3 += w3[j] * __half2float(v3[j]);
        }
    }

    // l2norm of aggr (4 independent wave reductions)
    float s0 = acc0 * acc0, s1 = acc1 * acc1, s2 = acc2 * acc2, s3 = acc3 * acc3;
    #pragma unroll
    for (int off = 32; off > 0; off >>= 1) {
        s0 += __shfl_xor(s0, off);
        s1 += __shfl_xor(s1, off);
        s2 += __shfl_xor(s2, off);
        s3 += __shfl_xor(s3, off);
    }
    float an0 = acc0 / fmaxf(sqrtf(s0), 1e-12f);
    float an1 = acc1 / fmaxf(sqrtf(s1), 1e-12f);
    float an2 = acc2 / fmaxf(sqrtf(s2), 1e-12f);
    float an3 = acc3 / fmaxf(sqrtf(s3), 1e-12f);

    float o0 = bias, o1 = bias, o2 = bias, o3 = bias;
    #pragma unroll
    for (int k = 0; k < 64; ++k) {
        float wk = Ws[k * 64 + lane];
        o0 += rl(an0, k) * wk;
        o1 += rl(an1, k) * wk;
        o2 += rl(an2, k) * wk;
        o3 += rl(an3, k) * wk;
    }
    #pragma unroll
    for (int k = 0; k < 64; ++k) {
        float wk = Ws[(64 + k) * 64 + lane];
        o0 += rl(xl0, k) * wk;
        o1 += rl(xl1, k) * wk;
        o2 += rl(xl2, k) * wk;
        o3 += rl(xl3, k) * wk;
    }

    float q0 = o0 * o0, q1 = o1 * o1, q2 = o2 * o2, q3 = o3 * o3;
    #pragma unroll
    for (int off = 32; off > 0; off >>= 1) {
        q0 += __shfl_xor(q0, off);
        q1 += __shfl_xor(q1, off);
        q2 += __shfl_xor(q2, off);
        q3 += __shfl_xor(q3, off);
    }
    o0 /= fmaxf(sqrtf(q0), 1e-12f);
    o1 /= fmaxf(sqrtf(q1), 1e-12f);
    o2 /= fmaxf(sqrtf(q2), 1e-12f);
    o3 /= fmaxf(sqrtf(q3), 1e-12f);

    if (nbase + 0 < NN) {
        xout[(size_t)(nbase + 0) * DD + lane] = o0;
        xout16[(size_t)(nbase + 0) * DD + lane] = __float2half(o0);
    }
    if (nbase + 1 < NN) {
        xout[(size_t)(nbase + 1) * DD + lane] = o1;
        xout16[(size_t)(nbase + 1) * DD + lane] = __float2half(o1);
    }
    if (nbase + 2 < NN) {
        xout[(size_t)(nbase + 2) * DD + lane] = o2;
        xout16[(size_t)(nbase + 2) * DD + lane] = __float2half(o2);
    }
    if (nbase + 3 < NN) {
        xout[(size_t)(nbase + 3) * DD + lane] = o3;
        xout16[(size_t)(nbase + 3) * DD + lane] = __float2half(o3);
    }
}

// ---------------------------------------------------------------------------
extern "C" void kernel_launch(void* const* d_in, const int* in_sizes, int n_in,
                              void* d_out, int out_size, void* d_ws, size_t ws_size,
                              hipStream_t stream) {
    const float* x0  = (const float*)d_in[0];
    const void*  eidx = d_in[1];
    const float* ew  = (const float*)d_in[2];
    const float* W   = (const float*)d_in[3];
    const float* b   = (const float*)d_in[4];
    float* out = (float*)d_out;

    char* p = (char*)d_ws;
    auto alloc = [&](size_t bytes) {
        char* r = p;
        p += (bytes + 255) & ~(size_t)255;
        return r;
    };
    int*    flag   = (int*)alloc(4);
    int*    cnt    = (int*)alloc((size_t)NN * 4);
    int*    offs   = (int*)alloc((size_t)(NN + 1) * 4);
    int*    cursor = (int*)alloc((size_t)NN * 4);
    int2*   csr    = (int2*)alloc((size_t)NE * 8);
    float*  bufA   = (float*)alloc((size_t)NN * DD * 4);
    __half* x16a   = (__half*)alloc((size_t)NN * DD * 2);
    __half* x16b   = (__half*)alloc((size_t)NN * DD * 2);

    hipMemsetAsync(cnt, 0, (size_t)NN * 4, stream);
    detect_i64<<<1, 256, 0, stream>>>((const unsigned int*)eidx, flag);
    hist_k<<<(NE + 255) / 256, 256, 0, stream>>>(eidx, flag, cnt);
    scan_k<<<1, 1024, 0, stream>>>(cnt, offs, cursor);
    fill_k<<<(NE + 255) / 256, 256, 0, stream>>>(eidx, ew, flag, cursor, csr);
    cvt_k<<<(NN * DD / 4 + 255) / 256, 256, 0, stream>>>(x0, x16a);

    int nblk = (NN + 31) / 32;
    for (int i = 0; i < NL; ++i) {
        const float* xin  = (i == 0) ? x0 : ((i % 2 == 1) ? bufA : out);
        float*       xout = (i % 2 == 0) ? bufA : out;
        const __half* xi16 = (i % 2 == 0) ? x16a : x16b;
        __half*       xo16 = (i % 2 == 0) ? x16b : x16a;
        layer_k<<<nblk, 512, 0, stream>>>(xin, xi16, W + (size_t)i * 128 * 64,
                                          b + (size_t)i * 64, offs, csr, xout, xo16);
    }
}

// Round 6
// 919.447 us; speedup vs baseline: 2.1175x; 2.1175x over previous
//
#include <hip/hip_runtime.h>
#include <hip/hip_fp16.h>

#define NN 50000
#define NE 800000
#define NL 12
#define DD 64

__device__ __forceinline__ float rl(float v, int k) {
    return __int_as_float(__builtin_amdgcn_readlane(__float_as_int(v), k));
}

// ---------------------------------------------------------------------------
// Detect whether edge_index is stored as int64 (odd 32-bit words all zero).
// ---------------------------------------------------------------------------
__global__ __launch_bounds__(256) void detect_i64(const unsigned int* __restrict__ w,
                                                  int* __restrict__ flag) {
    __shared__ unsigned int red[256];
    unsigned int v = 0;
    for (int i = threadIdx.x; i < 4096; i += 256) v |= w[2 * i + 1];
    red[threadIdx.x] = v;
    __syncthreads();
    for (int s = 128; s > 0; s >>= 1) {
        if (threadIdx.x < s) red[threadIdx.x] |= red[threadIdx.x + s];
        __syncthreads();
    }
    if (threadIdx.x == 0) *flag = (red[0] == 0u) ? 1 : 0;
}

__global__ __launch_bounds__(256) void hist_k(const void* __restrict__ eidx,
                                              const int* __restrict__ flag,
                                              int* __restrict__ cnt) {
    int e = blockIdx.x * 256 + threadIdx.x;
    if (e >= NE) return;
    int dst;
    if (*flag) dst = (int)((const long long*)eidx)[NE + e];
    else       dst = ((const int*)eidx)[NE + e];
    atomicAdd(&cnt[dst], 1);
}

__global__ __launch_bounds__(1024) void scan_k(const int* __restrict__ cnt,
                                               int* __restrict__ offs,
                                               int* __restrict__ cursor) {
    __shared__ int wsum[16];
    __shared__ int carry_s;
    int tid = threadIdx.x;
    int lane = tid & 63;
    int wv = tid >> 6;
    if (tid == 0) carry_s = 0;
    __syncthreads();
    for (int base = 0; base < NN; base += 1024) {
        int i = base + tid;
        int v = (i < NN) ? cnt[i] : 0;
        int incl = v;
        #pragma unroll
        for (int d = 1; d < 64; d <<= 1) {
            int t = __shfl_up(incl, d);
            if (lane >= d) incl += t;
        }
        if (lane == 63) wsum[wv] = incl;
        __syncthreads();
        if (wv == 0) {
            int s = (lane < 16) ? wsum[lane] : 0;
            #pragma unroll
            for (int d = 1; d < 16; d <<= 1) {
                int t = __shfl_up(s, d);
                if (lane >= d) s += t;
            }
            if (lane < 16) wsum[lane] = s;
        }
        __syncthreads();
        int wbase = (wv == 0) ? 0 : wsum[wv - 1];
        int carry = carry_s;
        int excl = carry + wbase + incl - v;
        if (i < NN) { offs[i] = excl; cursor[i] = excl; }
        __syncthreads();
        if (tid == 1023) carry_s = carry + wsum[15];
        __syncthreads();
    }
    if (threadIdx.x == 0) offs[NN] = carry_s;
}

__global__ __launch_bounds__(256) void fill_k(const void* __restrict__ eidx,
                                              const float* __restrict__ ew,
                                              const int* __restrict__ flag,
                                              int* __restrict__ cursor,
                                              int2* __restrict__ csr) {
    int e = blockIdx.x * 256 + threadIdx.x;
    if (e >= NE) return;
    int src, dst;
    if (*flag) {
        const long long* p = (const long long*)eidx;
        src = (int)p[e];
        dst = (int)p[NE + e];
    } else {
        const int* p = (const int*)eidx;
        src = p[e];
        dst = p[NE + e];
    }
    int pos = atomicAdd(&cursor[dst], 1);
    csr[pos] = make_int2(src, __float_as_int(ew[e]));
}

// ---------------------------------------------------------------------------
// One-shot fp32 -> fp16 conversion of x0 (gather shadow copy).
// ---------------------------------------------------------------------------
__global__ __launch_bounds__(256) void cvt_k(const float* __restrict__ x,
                                             __half* __restrict__ y) {
    int i = blockIdx.x * 256 + threadIdx.x;      // indexes float4 groups
    if (i >= NN * DD / 4) return;
    float4 v = ((const float4*)x)[i];
    __half2 a = __floats2half2_rn(v.x, v.y);
    __half2 b = __floats2half2_rn(v.z, v.w);
    ((__half2*)y)[2 * i]     = a;
    ((__half2*)y)[2 * i + 1] = b;
}

// ---------------------------------------------------------------------------
// Fused layer. 512 threads, 8 waves, 4 nodes/wave.
// GATHER (restructured this round): lanes = 8 edge-slots (e8=lane>>3) x
// 8 chunks (c8=lane&7). One float4 (16B = 8 fp16) per lane -> one wave
// instruction fetches EIGHT edges' 128B rows; one int2 csr load covers
// 8 edges. VMEM instruction count per layer drops ~6.4x (the R2/R3/R5
// invariant showed time tracks instruction count, not bytes).
// Per-lane acc[8] = channels [8*c8, 8*c8+8), partial over edge-slots;
// reduced with shfl_xor {8,16,32}; norm with shfl_xor {1,2,4}.
// MLP: identical structure to R5 (W in LDS, readlane broadcast);
// an[k] = readlane(acc[k&7], k>>3).
// ---------------------------------------------------------------------------
__global__ __launch_bounds__(512) void layer_k(const float* __restrict__ xin,
                                               const __half* __restrict__ xin16,
                                               const float* __restrict__ Wl,
                                               const float* __restrict__ bl,
                                               const int* __restrict__ offs,
                                               const int2* __restrict__ csr,
                                               float* __restrict__ xout,
                                               __half* __restrict__ xout16) {
    __shared__ float Ws[128 * 64];
    int tid = threadIdx.x;
    const float4* Wv = (const float4*)Wl;
    float4* Wsv = (float4*)Ws;
    #pragma unroll
    for (int i = 0; i < 4; ++i) Wsv[tid + 512 * i] = Wv[tid + 512 * i];
    __syncthreads();

    int wave = tid >> 6;
    int lane = tid & 63;
    int e8 = lane >> 3;    // edge sub-slot 0..7
    int c8 = lane & 7;     // chunk: channels [8*c8, 8*c8+8)
    int nbase = blockIdx.x * 32 + wave * 4;

    int n0 = min(nbase + 0, NN - 1);
    int n1 = min(nbase + 1, NN - 1);
    int n2 = min(nbase + 2, NN - 1);
    int n3 = min(nbase + 3, NN - 1);

    float xl0 = xin[(size_t)n0 * DD + lane];
    float xl1 = xin[(size_t)n1 * DD + lane];
    float xl2 = xin[(size_t)n2 * DD + lane];
    float xl3 = xin[(size_t)n3 * DD + lane];
    float bias = bl[lane];

    int a0 = offs[n0], a1 = offs[n0 + 1];
    int b0 = offs[n1], b1 = offs[n1 + 1];
    int c0 = offs[n2], c1 = offs[n2 + 1];
    int d0 = offs[n3], d1 = offs[n3 + 1];
    int mx = max(max((a1 - a0 + 7) >> 3, (b1 - b0 + 7) >> 3),
                 max((c1 - c0 + 7) >> 3, (d1 - d0 + 7) >> 3));

    float acc0[8] = {0.f, 0.f, 0.f, 0.f, 0.f, 0.f, 0.f, 0.f};
    float acc1[8] = {0.f, 0.f, 0.f, 0.f, 0.f, 0.f, 0.f, 0.f};
    float acc2[8] = {0.f, 0.f, 0.f, 0.f, 0.f, 0.f, 0.f, 0.f};
    float acc3[8] = {0.f, 0.f, 0.f, 0.f, 0.f, 0.f, 0.f, 0.f};

    #pragma unroll 2
    for (int it = 0; it < mx; ++it) {
        int ebase = it * 8 + e8;
        int e;
        int2 sw;
        // issue all 8 VMEM instructions (4 csr + 4 row-gathers) up front
        e = a0 + ebase;
        sw = csr[(e < a1) ? e : 0];
        float w0 = (e < a1) ? __int_as_float(sw.y) : 0.f;
        float4 r0 = *(const float4*)(xin16 + ((size_t)sw.x << 6) + (c8 << 3));
        e = b0 + ebase;
        sw = csr[(e < b1) ? e : 0];
        float w1 = (e < b1) ? __int_as_float(sw.y) : 0.f;
        float4 r1 = *(const float4*)(xin16 + ((size_t)sw.x << 6) + (c8 << 3));
        e = c0 + ebase;
        sw = csr[(e < c1) ? e : 0];
        float w2 = (e < c1) ? __int_as_float(sw.y) : 0.f;
        float4 r2 = *(const float4*)(xin16 + ((size_t)sw.x << 6) + (c8 << 3));
        e = d0 + ebase;
        sw = csr[(e < d1) ? e : 0];
        float w3 = (e < d1) ? __int_as_float(sw.y) : 0.f;
        float4 r3 = *(const float4*)(xin16 + ((size_t)sw.x << 6) + (c8 << 3));

        const __half2* h0 = (const __half2*)&r0;
        const __half2* h1 = (const __half2*)&r1;
        const __half2* h2 = (const __half2*)&r2;
        const __half2* h3 = (const __half2*)&r3;
        #pragma unroll
        for (int i = 0; i < 4; ++i) {
            float2 f0 = __half22float2(h0[i]);
            float2 f1 = __half22float2(h1[i]);
            float2 f2 = __half22float2(h2[i]);
            float2 f3 = __half22float2(h3[i]);
            acc0[2 * i]     += w0 * f0.x;
            acc0[2 * i + 1] += w0 * f0.y;
            acc1[2 * i]     += w1 * f1.x;
            acc1[2 * i + 1] += w1 * f1.y;
            acc2[2 * i]     += w2 * f2.x;
            acc2[2 * i + 1] += w2 * f2.y;
            acc3[2 * i]     += w3 * f3.x;
            acc3[2 * i + 1] += w3 * f3.y;
        }
    }

    // reduce partial sums across the 8 edge-slots (lane bits 3..5)
    #pragma unroll
    for (int i = 0; i < 8; ++i) {
        acc0[i] += __shfl_xor(acc0[i], 8);
        acc1[i] += __shfl_xor(acc1[i], 8);
        acc2[i] += __shfl_xor(acc2[i], 8);
        acc3[i] += __shfl_xor(acc3[i], 8);
        acc0[i] += __shfl_xor(acc0[i], 16);
        acc1[i] += __shfl_xor(acc1[i], 16);
        acc2[i] += __shfl_xor(acc2[i], 16);
        acc3[i] += __shfl_xor(acc3[i], 16);
        acc0[i] += __shfl_xor(acc0[i], 32);
        acc1[i] += __shfl_xor(acc1[i], 32);
        acc2[i] += __shfl_xor(acc2[i], 32);
        acc3[i] += __shfl_xor(acc3[i], 32);
    }

    // l2 norms: per-lane partial (8 channels) then sum across c8 (bits 0..2)
    float s0 = 0.f, s1 = 0.f, s2 = 0.f, s3 = 0.f;
    #pragma unroll
    for (int i = 0; i < 8; ++i) {
        s0 += acc0[i] * acc0[i];
        s1 += acc1[i] * acc1[i];
        s2 += acc2[i] * acc2[i];
        s3 += acc3[i] * acc3[i];
    }
    #pragma unroll
    for (int off = 1; off <= 4; off <<= 1) {
        s0 += __shfl_xor(s0, off);
        s1 += __shfl_xor(s1, off);
        s2 += __shfl_xor(s2, off);
        s3 += __shfl_xor(s3, off);
    }
    float i0 = 1.f / fmaxf(sqrtf(s0), 1e-12f);
    float i1 = 1.f / fmaxf(sqrtf(s1), 1e-12f);
    float i2 = 1.f / fmaxf(sqrtf(s2), 1e-12f);
    float i3 = 1.f / fmaxf(sqrtf(s3), 1e-12f);
    #pragma unroll
    for (int i = 0; i < 8; ++i) {
        acc0[i] *= i0;
        acc1[i] *= i1;
        acc2[i] *= i2;
        acc3[i] *= i3;
    }

    float o0 = bias, o1 = bias, o2 = bias, o3 = bias;
    #pragma unroll
    for (int k = 0; k < 64; ++k) {
        float wk = Ws[k * 64 + lane];
        o0 += rl(acc0[k & 7], k >> 3) * wk;
        o1 += rl(acc1[k & 7], k >> 3) * wk;
        o2 += rl(acc2[k & 7], k >> 3) * wk;
        o3 += rl(acc3[k & 7], k >> 3) * wk;
    }
    #pragma unroll
    for (int k = 0; k < 64; ++k) {
        float wk = Ws[(64 + k) * 64 + lane];
        o0 += rl(xl0, k) * wk;
        o1 += rl(xl1, k) * wk;
        o2 += rl(xl2, k) * wk;
        o3 += rl(xl3, k) * wk;
    }

    float q0 = o0 * o0, q1 = o1 * o1, q2 = o2 * o2, q3 = o3 * o3;
    #pragma unroll
    for (int off = 32; off > 0; off >>= 1) {
        q0 += __shfl_xor(q0, off);
        q1 += __shfl_xor(q1, off);
        q2 += __shfl_xor(q2, off);
        q3 += __shfl_xor(q3, off);
    }
    o0 /= fmaxf(sqrtf(q0), 1e-12f);
    o1 /= fmaxf(sqrtf(q1), 1e-12f);
    o2 /= fmaxf(sqrtf(q2), 1e-12f);
    o3 /= fmaxf(sqrtf(q3), 1e-12f);

    if (nbase + 0 < NN) {
        xout[(size_t)(nbase + 0) * DD + lane] = o0;
        xout16[(size_t)(nbase + 0) * DD + lane] = __float2half(o0);
    }
    if (nbase + 1 < NN) {
        xout[(size_t)(nbase + 1) * DD + lane] = o1;
        xout16[(size_t)(nbase + 1) * DD + lane] = __float2half(o1);
    }
    if (nbase + 2 < NN) {
        xout[(size_t)(nbase + 2) * DD + lane] = o2;
        xout16[(size_t)(nbase + 2) * DD + lane] = __float2half(o2);
    }
    if (nbase + 3 < NN) {
        xout[(size_t)(nbase + 3) * DD + lane] = o3;
        xout16[(size_t)(nbase + 3) * DD + lane] = __float2half(o3);
    }
}

// ---------------------------------------------------------------------------
extern "C" void kernel_launch(void* const* d_in, const int* in_sizes, int n_in,
                              void* d_out, int out_size, void* d_ws, size_t ws_size,
                              hipStream_t stream) {
    const float* x0  = (const float*)d_in[0];
    const void*  eidx = d_in[1];
    const float* ew  = (const float*)d_in[2];
    const float* W   = (const float*)d_in[3];
    const float* b   = (const float*)d_in[4];
    float* out = (float*)d_out;

    char* p = (char*)d_ws;
    auto alloc = [&](size_t bytes) {
        char* r = p;
        p += (bytes + 255) & ~(size_t)255;
        return r;
    };
    int*    flag   = (int*)alloc(4);
    int*    cnt    = (int*)alloc((size_t)NN * 4);
    int*    offs   = (int*)alloc((size_t)(NN + 1) * 4);
    int*    cursor = (int*)alloc((size_t)NN * 4);
    int2*   csr    = (int2*)alloc((size_t)NE * 8);
    float*  bufA   = (float*)alloc((size_t)NN * DD * 4);
    __half* x16a   = (__half*)alloc((size_t)NN * DD * 2);
    __half* x16b   = (__half*)alloc((size_t)NN * DD * 2);

    hipMemsetAsync(cnt, 0, (size_t)NN * 4, stream);
    detect_i64<<<1, 256, 0, stream>>>((const unsigned int*)eidx, flag);
    hist_k<<<(NE + 255) / 256, 256, 0, stream>>>(eidx, flag, cnt);
    scan_k<<<1, 1024, 0, stream>>>(cnt, offs, cursor);
    fill_k<<<(NE + 255) / 256, 256, 0, stream>>>(eidx, ew, flag, cursor, csr);
    cvt_k<<<(NN * DD / 4 + 255) / 256, 256, 0, stream>>>(x0, x16a);

    int nblk = (NN + 31) / 32;
    for (int i = 0; i < NL; ++i) {
        const float* xin  = (i == 0) ? x0 : ((i % 2 == 1) ? bufA : out);
        float*       xout = (i % 2 == 0) ? bufA : out;
        const __half* xi16 = (i % 2 == 0) ? x16a : x16b;
        __half*       xo16 = (i % 2 == 0) ? x16b : x16a;
        layer_k<<<nblk, 512, 0, stream>>>(xin, xi16, W + (size_t)i * 128 * 64,
                                          b + (size_t)i * 64, offs, csr, xout, xo16);
    }
}

// Round 9
// 678.010 us; speedup vs baseline: 2.8716x; 1.3561x over previous
//
#include <hip/hip_runtime.h>
#include <hip/hip_fp16.h>

#define NN 50000
#define NE 800000
#define NL 12
#define DD 64

typedef _Float16 f16x8 __attribute__((ext_vector_type(8)));
typedef float f32x4 __attribute__((ext_vector_type(4)));

// ---------------------------------------------------------------------------
// Detect whether edge_index is stored as int64 (odd 32-bit words all zero).
// ---------------------------------------------------------------------------
__global__ __launch_bounds__(256) void detect_i64(const unsigned int* __restrict__ w,
                                                  int* __restrict__ flag) {
    __shared__ unsigned int red[256];
    unsigned int v = 0;
    for (int i = threadIdx.x; i < 4096; i += 256) v |= w[2 * i + 1];
    red[threadIdx.x] = v;
    __syncthreads();
    for (int s = 128; s > 0; s >>= 1) {
        if (threadIdx.x < s) red[threadIdx.x] |= red[threadIdx.x + s];
        __syncthreads();
    }
    if (threadIdx.x == 0) *flag = (red[0] == 0u) ? 1 : 0;
}

__global__ __launch_bounds__(256) void hist_k(const void* __restrict__ eidx,
                                              const int* __restrict__ flag,
                                              int* __restrict__ cnt) {
    int e = blockIdx.x * 256 + threadIdx.x;
    if (e >= NE) return;
    int dst;
    if (*flag) dst = (int)((const long long*)eidx)[NE + e];
    else       dst = ((const int*)eidx)[NE + e];
    atomicAdd(&cnt[dst], 1);
}

__global__ __launch_bounds__(1024) void scan_k(const int* __restrict__ cnt,
                                               int* __restrict__ offs,
                                               int* __restrict__ cursor) {
    __shared__ int wsum[16];
    __shared__ int carry_s;
    int tid = threadIdx.x;
    int lane = tid & 63;
    int wv = tid >> 6;
    if (tid == 0) carry_s = 0;
    __syncthreads();
    for (int base = 0; base < NN; base += 1024) {
        int i = base + tid;
        int v = (i < NN) ? cnt[i] : 0;
        int incl = v;
        #pragma unroll
        for (int d = 1; d < 64; d <<= 1) {
            int t = __shfl_up(incl, d);
            if (lane >= d) incl += t;
        }
        if (lane == 63) wsum[wv] = incl;
        __syncthreads();
        if (wv == 0) {
            int s = (lane < 16) ? wsum[lane] : 0;
            #pragma unroll
            for (int d = 1; d < 16; d <<= 1) {
                int t = __shfl_up(s, d);
                if (lane >= d) s += t;
            }
            if (lane < 16) wsum[lane] = s;
        }
        __syncthreads();
        int wbase = (wv == 0) ? 0 : wsum[wv - 1];
        int carry = carry_s;
        int excl = carry + wbase + incl - v;
        if (i < NN) { offs[i] = excl; cursor[i] = excl; }
        __syncthreads();
        if (tid == 1023) carry_s = carry + wsum[15];
        __syncthreads();
    }
    if (threadIdx.x == 0) offs[NN] = carry_s;
}

// ---------------------------------------------------------------------------
// Scatter edges into 4-byte CSR slots: {u16 src, fp16 weight}.
// ---------------------------------------------------------------------------
__global__ __launch_bounds__(256) void fill_k(const void* __restrict__ eidx,
                                              const float* __restrict__ ew,
                                              const int* __restrict__ flag,
                                              int* __restrict__ cursor,
                                              unsigned int* __restrict__ csr4) {
    int e = blockIdx.x * 256 + threadIdx.x;
    if (e >= NE) return;
    int src, dst;
    if (*flag) {
        const long long* p = (const long long*)eidx;
        src = (int)p[e];
        dst = (int)p[NE + e];
    } else {
        const int* p = (const int*)eidx;
        src = p[e];
        dst = p[NE + e];
    }
    int pos = atomicAdd(&cursor[dst], 1);
    unsigned short wb = __half_as_ushort(__float2half(ew[e]));
    csr4[pos] = (unsigned int)(src & 0xFFFF) | ((unsigned int)wb << 16);
}

// ---------------------------------------------------------------------------
// One-shot fp32 -> fp16 conversion of x0 (gather shadow copy).
// ---------------------------------------------------------------------------
__global__ __launch_bounds__(256) void cvt_k(const float* __restrict__ x,
                                             __half* __restrict__ y) {
    int i = blockIdx.x * 256 + threadIdx.x;
    if (i >= NN * DD / 4) return;
    float4 v = ((const float4*)x)[i];
    __half2 a = __floats2half2_rn(v.x, v.y);
    __half2 b = __floats2half2_rn(v.z, v.w);
    ((__half2*)y)[2 * i]     = a;
    ((__half2*)y)[2 * i + 1] = b;
}

// ---------------------------------------------------------------------------
// One-shot: W (fp32 [NL][128][64]) -> fp16 B-fragment order for
// mfma_f32_16x16x32_f16: Wfrag[(l*4+kb)*4+nt][lane][j] = W[l][kb*32+(lane>>4)*8+j][nt*16+(lane&15)]
// ---------------------------------------------------------------------------
__global__ __launch_bounds__(256) void wfrag_k(const float* __restrict__ W,
                                               __half* __restrict__ Wfrag) {
    int t = blockIdx.x * 256 + threadIdx.x;
    if (t >= NL * 1024) return;
    int l    = t >> 10;
    int kb   = (t >> 8) & 3;
    int nt   = (t >> 6) & 3;
    int lane = t & 63;
    int kg = lane >> 4, n = nt * 16 + (lane & 15);
    const float* Wl = W + (size_t)l * 128 * 64;
    __half* dst = Wfrag + (size_t)t * 8;
    #pragma unroll
    for (int j = 0; j < 8; ++j) {
        int k = kb * 32 + kg * 8 + j;
        dst[j] = __float2half(Wl[k * 64 + n]);
    }
}

// ---------------------------------------------------------------------------
// Fused layer. 256 threads = 4 waves; each wave owns 16 nodes, independent
// (ZERO barriers). Per wave:
//   phase 1: 4 gather-quads (R6 structure: 8 edge-slots x 8 chunks, 4B csr),
//            l2norm, write normalized aggr (fp16) to XOR-swizzled LDS rows.
//   phase 2: MFMA MLP: D(16x64) = [an | x16] (16x128 fp16) @ Wfrag, K=128
//            via 16x mfma_f32_16x16x32_f16; f32 bias + l2norm epilogue.
// fp16-only chaining: f32 output written ONLY on the last layer (d_out).
// ---------------------------------------------------------------------------
__global__ __launch_bounds__(256) void layer_k(const __half* __restrict__ xin16,
                                               const __half* __restrict__ Wfl,
                                               const float* __restrict__ bl,
                                               const int* __restrict__ offs,
                                               const unsigned int* __restrict__ csr4,
                                               __half* __restrict__ xout16,
                                               float* __restrict__ fout,
                                               int writeF32) {
    __shared__ __align__(16) __half an_lds[4 * 16 * 64];  // 8 KB
    int tid = threadIdx.x;
    int wave = tid >> 6, lane = tid & 63;
    int e8 = lane >> 3, c8 = lane & 7;
    int kg = lane >> 4, l15 = lane & 15;
    int nb16 = blockIdx.x * 64 + wave * 16;

    // ---------------- phase 1: gather 4 quads ----------------
    for (int q = 0; q < 4; ++q) {
        int nq = nb16 + q * 4;
        int n0 = min(nq + 0, NN - 1);
        int n1 = min(nq + 1, NN - 1);
        int n2 = min(nq + 2, NN - 1);
        int n3 = min(nq + 3, NN - 1);
        int a0 = offs[n0], a1 = offs[n0 + 1];
        int b0 = offs[n1], b1 = offs[n1 + 1];
        int c0 = offs[n2], c1 = offs[n2 + 1];
        int d0 = offs[n3], d1 = offs[n3 + 1];
        int mx = max(max((a1 - a0 + 7) >> 3, (b1 - b0 + 7) >> 3),
                     max((c1 - c0 + 7) >> 3, (d1 - d0 + 7) >> 3));

        float acc0[8] = {0.f,0.f,0.f,0.f,0.f,0.f,0.f,0.f};
        float acc1[8] = {0.f,0.f,0.f,0.f,0.f,0.f,0.f,0.f};
        float acc2[8] = {0.f,0.f,0.f,0.f,0.f,0.f,0.f,0.f};
        float acc3[8] = {0.f,0.f,0.f,0.f,0.f,0.f,0.f,0.f};

        #pragma unroll 2
        for (int it = 0; it < mx; ++it) {
            int eb = it * 8 + e8;
            int e;
            unsigned int u;
            e = a0 + eb;
            u = csr4[(e < a1) ? e : 0];
            float w0 = (e < a1) ? __half2float(__ushort_as_half((unsigned short)(u >> 16))) : 0.f;
            float4 r0 = *(const float4*)(xin16 + ((size_t)(u & 0xFFFFu) << 6) + (c8 << 3));
            e = b0 + eb;
            u = csr4[(e < b1) ? e : 0];
            float w1 = (e < b1) ? __half2float(__ushort_as_half((unsigned short)(u >> 16))) : 0.f;
            float4 r1 = *(const float4*)(xin16 + ((size_t)(u & 0xFFFFu) << 6) + (c8 << 3));
            e = c0 + eb;
            u = csr4[(e < c1) ? e : 0];
            float w2 = (e < c1) ? __half2float(__ushort_as_half((unsigned short)(u >> 16))) : 0.f;
            float4 r2 = *(const float4*)(xin16 + ((size_t)(u & 0xFFFFu) << 6) + (c8 << 3));
            e = d0 + eb;
            u = csr4[(e < d1) ? e : 0];
            float w3 = (e < d1) ? __half2float(__ushort_as_half((unsigned short)(u >> 16))) : 0.f;
            float4 r3 = *(const float4*)(xin16 + ((size_t)(u & 0xFFFFu) << 6) + (c8 << 3));

            const __half2* h0 = (const __half2*)&r0;
            const __half2* h1 = (const __half2*)&r1;
            const __half2* h2 = (const __half2*)&r2;
            const __half2* h3 = (const __half2*)&r3;
            #pragma unroll
            for (int i = 0; i < 4; ++i) {
                float2 f0 = __half22float2(h0[i]);
                float2 f1 = __half22float2(h1[i]);
                float2 f2 = __half22float2(h2[i]);
                float2 f3 = __half22float2(h3[i]);
                acc0[2*i]   += w0 * f0.x;  acc0[2*i+1] += w0 * f0.y;
                acc1[2*i]   += w1 * f1.x;  acc1[2*i+1] += w1 * f1.y;
                acc2[2*i]   += w2 * f2.x;  acc2[2*i+1] += w2 * f2.y;
                acc3[2*i]   += w3 * f3.x;  acc3[2*i+1] += w3 * f3.y;
            }
        }

        // reduce partial sums across the 8 edge-slots (lane bits 3..5)
        #pragma unroll
        for (int i = 0; i < 8; ++i) {
            acc0[i] += __shfl_xor(acc0[i], 8);
            acc1[i] += __shfl_xor(acc1[i], 8);
            acc2[i] += __shfl_xor(acc2[i], 8);
            acc3[i] += __shfl_xor(acc3[i], 8);
            acc0[i] += __shfl_xor(acc0[i], 16);
            acc1[i] += __shfl_xor(acc1[i], 16);
            acc2[i] += __shfl_xor(acc2[i], 16);
            acc3[i] += __shfl_xor(acc3[i], 16);
            acc0[i] += __shfl_xor(acc0[i], 32);
            acc1[i] += __shfl_xor(acc1[i], 32);
            acc2[i] += __shfl_xor(acc2[i], 32);
            acc3[i] += __shfl_xor(acc3[i], 32);
        }

        // l2 norm per node: per-lane partial then sum across c8 (bits 0..2)
        float s0 = 0.f, s1 = 0.f, s2 = 0.f, s3 = 0.f;
        #pragma unroll
        for (int i = 0; i < 8; ++i) {
            s0 += acc0[i] * acc0[i];
            s1 += acc1[i] * acc1[i];
            s2 += acc2[i] * acc2[i];
            s3 += acc3[i] * acc3[i];
        }
        #pragma unroll
        for (int off = 1; off <= 4; off <<= 1) {
            s0 += __shfl_xor(s0, off);
            s1 += __shfl_xor(s1, off);
            s2 += __shfl_xor(s2, off);
            s3 += __shfl_xor(s3, off);
        }
        float i0 = 1.f / fmaxf(sqrtf(s0), 1e-12f);
        float i1 = 1.f / fmaxf(sqrtf(s1), 1e-12f);
        float i2 = 1.f / fmaxf(sqrtf(s2), 1e-12f);
        float i3 = 1.f / fmaxf(sqrtf(s3), 1e-12f);
        #pragma unroll
        for (int i = 0; i < 8; ++i) {
            acc0[i] *= i0; acc1[i] *= i1; acc2[i] *= i2; acc3[i] *= i3;
        }

        // write quad's normalized aggr to LDS (fp16, XOR-swizzled 16B slots)
        if (e8 < 4) {
            float ts[8];
            #pragma unroll
            for (int i = 0; i < 8; ++i) {
                float v = acc3[i];
                v = (e8 == 2) ? acc2[i] : v;
                v = (e8 == 1) ? acc1[i] : v;
                v = (e8 == 0) ? acc0[i] : v;
                ts[i] = v;
            }
            int row = q * 4 + e8;
            int slot = c8 ^ (row & 7);
            __half2 p0 = __floats2half2_rn(ts[0], ts[1]);
            __half2 p1 = __floats2half2_rn(ts[2], ts[3]);
            __half2 p2 = __floats2half2_rn(ts[4], ts[5]);
            __half2 p3 = __floats2half2_rn(ts[6], ts[7]);
            uint4 pk;
            pk.x = *(unsigned int*)&p0;
            pk.y = *(unsigned int*)&p1;
            pk.z = *(unsigned int*)&p2;
            pk.w = *(unsigned int*)&p3;
            *((uint4*)&an_lds[((wave * 16 + row) << 6) + (slot << 3)]) = pk;
        }
    }

    // ---------------- phase 2: MFMA MLP ----------------
    // A (16 nodes x K=128) = [an(0..63) | x16(0..63)]; B = Wfrag; D = 16x64.
    f32x4 C0 = {0.f,0.f,0.f,0.f};
    f32x4 C1 = {0.f,0.f,0.f,0.f};
    f32x4 C2 = {0.f,0.f,0.f,0.f};
    f32x4 C3 = {0.f,0.f,0.f,0.f};
    int nodeA = min(nb16 + l15, NN - 1);
    #pragma unroll
    for (int kb = 0; kb < 4; ++kb) {
        f16x8 af;
        if (kb < 2) {
            int sl = kb * 4 + kg;
            af = *(const f16x8*)&an_lds[((wave * 16 + l15) << 6) + ((sl ^ (l15 & 7)) << 3)];
        } else {
            af = *(const f16x8*)(xin16 + ((size_t)nodeA << 6) + ((kb - 2) * 32 + kg * 8));
        }
        const __half* wb = Wfl + (size_t)(kb * 4) * 512 + lane * 8;
        f16x8 bf0 = *(const f16x8*)(wb);
        f16x8 bf1 = *(const f16x8*)(wb + 512);
        f16x8 bf2 = *(const f16x8*)(wb + 1024);
        f16x8 bf3 = *(const f16x8*)(wb + 1536);
        C0 = __builtin_amdgcn_mfma_f32_16x16x32_f16(af, bf0, C0, 0, 0, 0);
        C1 = __builtin_amdgcn_mfma_f32_16x16x32_f16(af, bf1, C1, 0, 0, 0);
        C2 = __builtin_amdgcn_mfma_f32_16x16x32_f16(af, bf2, C2, 0, 0, 0);
        C3 = __builtin_amdgcn_mfma_f32_16x16x32_f16(af, bf3, C3, 0, 0, 0);
    }

    // epilogue: bias (f32), l2norm (f32), store fp16 (+f32 on last layer)
    float bn0 = bl[l15], bn1 = bl[16 + l15], bn2 = bl[32 + l15], bn3 = bl[48 + l15];
    #pragma unroll
    for (int r = 0; r < 4; ++r) {
        float v0 = C0[r] + bn0;
        float v1 = C1[r] + bn1;
        float v2 = C2[r] + bn2;
        float v3 = C3[r] + bn3;
        float t = v0 * v0 + v1 * v1 + v2 * v2 + v3 * v3;
        t += __shfl_xor(t, 1);
        t += __shfl_xor(t, 2);
        t += __shfl_xor(t, 4);
        t += __shfl_xor(t, 8);
        float inv = 1.f / fmaxf(sqrtf(t), 1e-12f);
        int node = nb16 + kg * 4 + r;
        if (node < NN) {
            size_t base = ((size_t)node << 6) + l15;
            xout16[base]      = __float2half(v0 * inv);
            xout16[base + 16] = __float2half(v1 * inv);
            xout16[base + 32] = __float2half(v2 * inv);
            xout16[base + 48] = __float2half(v3 * inv);
            if (writeF32) {
                fout[base]      = v0 * inv;
                fout[base + 16] = v1 * inv;
                fout[base + 32] = v2 * inv;
                fout[base + 48] = v3 * inv;
            }
        }
    }
}

// ---------------------------------------------------------------------------
extern "C" void kernel_launch(void* const* d_in, const int* in_sizes, int n_in,
                              void* d_out, int out_size, void* d_ws, size_t ws_size,
                              hipStream_t stream) {
    const float* x0  = (const float*)d_in[0];
    const void*  eidx = d_in[1];
    const float* ew  = (const float*)d_in[2];
    const float* W   = (const float*)d_in[3];
    const float* b   = (const float*)d_in[4];
    float* out = (float*)d_out;

    char* p = (char*)d_ws;
    auto alloc = [&](size_t bytes) {
        char* r = p;
        p += (bytes + 255) & ~(size_t)255;
        return r;
    };
    int*          flag   = (int*)alloc(4);
    int*          cnt    = (int*)alloc((size_t)NN * 4);
    int*          offs   = (int*)alloc((size_t)(NN + 1) * 4);
    int*          cursor = (int*)alloc((size_t)NN * 4);
    unsigned int* csr4   = (unsigned int*)alloc((size_t)NE * 4);
    __half*       x16a   = (__half*)alloc((size_t)NN * DD * 2);
    __half*       x16b   = (__half*)alloc((size_t)NN * DD * 2);
    __half*       Wfrag  = (__half*)alloc((size_t)NL * 8192 * 2);

    hipMemsetAsync(cnt, 0, (size_t)NN * 4, stream);
    detect_i64<<<1, 256, 0, stream>>>((const unsigned int*)eidx, flag);
    hist_k<<<(NE + 255) / 256, 256, 0, stream>>>(eidx, flag, cnt);
    scan_k<<<1, 1024, 0, stream>>>(cnt, offs, cursor);
    fill_k<<<(NE + 255) / 256, 256, 0, stream>>>(eidx, ew, flag, cursor, csr4);
    cvt_k<<<(NN * DD / 4 + 255) / 256, 256, 0, stream>>>(x0, x16a);
    wfrag_k<<<(NL * 1024 + 255) / 256, 256, 0, stream>>>(W, Wfrag);

    int nblk = (NN + 63) / 64;   // 64 nodes per 256-thread block
    for (int i = 0; i < NL; ++i) {
        const __half* xi = (i % 2 == 0) ? x16a : x16b;
        __half*       xo = (i % 2 == 0) ? x16b : x16a;
        layer_k<<<nblk, 256, 0, stream>>>(xi, Wfrag + (size_t)i * 8192,
                                          b + (size_t)i * 64, offs, csr4, xo,
                                          out, (i == NL - 1) ? 1 : 0);
    }
}

// Round 11
// 637.448 us; speedup vs baseline: 3.0543x; 1.0636x over previous
//
#include <hip/hip_runtime.h>
#include <hip/hip_fp16.h>

#define NN 50000
#define NE 800000
#define NL 12
#define DD 64
#define NBLK 49   // ceil(50000/1024) blocks of 256 threads x int4

typedef _Float16 f16x8 __attribute__((ext_vector_type(8)));
typedef float f32x4 __attribute__((ext_vector_type(4)));

// ---------------------------------------------------------------------------
// Detect whether edge_index is stored as int64 (odd 32-bit words all zero).
// ---------------------------------------------------------------------------
__global__ __launch_bounds__(256) void detect_i64(const unsigned int* __restrict__ w,
                                                  int* __restrict__ flag) {
    __shared__ unsigned int red[256];
    unsigned int v = 0;
    for (int i = threadIdx.x; i < 4096; i += 256) v |= w[2 * i + 1];
    red[threadIdx.x] = v;
    __syncthreads();
    for (int s = 128; s > 0; s >>= 1) {
        if (threadIdx.x < s) red[threadIdx.x] |= red[threadIdx.x + s];
        __syncthreads();
    }
    if (threadIdx.x == 0) *flag = (red[0] == 0u) ? 1 : 0;
}

__global__ __launch_bounds__(256) void hist_k(const void* __restrict__ eidx,
                                              const int* __restrict__ flag,
                                              int* __restrict__ cnt) {
    int e = blockIdx.x * 256 + threadIdx.x;
    if (e >= NE) return;
    int dst;
    if (*flag) dst = (int)((const long long*)eidx)[NE + e];
    else       dst = ((const int*)eidx)[NE + e];
    atomicAdd(&cnt[dst], 1);
}

// ---------------------------------------------------------------------------
// Multi-block scan, 3 phases (replaces the 50 us single-block scan).
// ---------------------------------------------------------------------------
__global__ __launch_bounds__(256) void part_k(const int* __restrict__ cnt,
                                              int* __restrict__ psum) {
    __shared__ int wls[4];
    int tid = threadIdx.x, lane = tid & 63, wv = tid >> 6;
    int idx4 = blockIdx.x * 256 + tid;
    int4 c = (idx4 < NN / 4) ? ((const int4*)cnt)[idx4] : make_int4(0, 0, 0, 0);
    int s = c.x + c.y + c.z + c.w;
    #pragma unroll
    for (int off = 32; off > 0; off >>= 1) s += __shfl_xor(s, off);
    if (lane == 0) wls[wv] = s;
    __syncthreads();
    if (tid == 0) psum[blockIdx.x] = wls[0] + wls[1] + wls[2] + wls[3];
}

__global__ __launch_bounds__(64) void pscan_k(const int* __restrict__ psum,
                                              int* __restrict__ pbase,
                                              int* __restrict__ offs) {
    int tid = threadIdx.x;
    int v = (tid < NBLK) ? psum[tid] : 0;
    int incl = v;
    #pragma unroll
    for (int d = 1; d < 64; d <<= 1) {
        int t = __shfl_up(incl, d);
        if (tid >= d) incl += t;
    }
    if (tid < NBLK) pbase[tid] = incl - v;
    if (tid == NBLK - 1) offs[NN] = incl;
}

__global__ __launch_bounds__(256) void offs_k(const int* __restrict__ cnt,
                                              const int* __restrict__ pbase,
                                              int* __restrict__ offs,
                                              int* __restrict__ cursor) {
    __shared__ int wls[4];
    int tid = threadIdx.x, lane = tid & 63, wv = tid >> 6;
    int idx4 = blockIdx.x * 256 + tid;
    int4 c = (idx4 < NN / 4) ? ((const int4*)cnt)[idx4] : make_int4(0, 0, 0, 0);
    int s = c.x + c.y + c.z + c.w;
    int incl = s;
    #pragma unroll
    for (int d = 1; d < 64; d <<= 1) {
        int t = __shfl_up(incl, d);
        if (lane >= d) incl += t;
    }
    if (lane == 63) wls[wv] = incl;
    __syncthreads();
    if (tid == 0) {
        int a = 0;
        #pragma unroll
        for (int j = 0; j < 4; ++j) { int t = wls[j]; wls[j] = a; a += t; }
    }
    __syncthreads();
    int base = pbase[blockIdx.x] + wls[wv] + incl - s;
    int4 o;
    o.x = base;
    o.y = o.x + c.x;
    o.z = o.y + c.y;
    o.w = o.z + c.z;
    if (idx4 < NN / 4) {
        ((int4*)offs)[idx4] = o;
        ((int4*)cursor)[idx4] = o;
    }
}

// ---------------------------------------------------------------------------
// Scatter edges into 4-byte CSR slots: {u16 src, fp16 weight}.
// ---------------------------------------------------------------------------
__global__ __launch_bounds__(256) void fill_k(const void* __restrict__ eidx,
                                              const float* __restrict__ ew,
                                              const int* __restrict__ flag,
                                              int* __restrict__ cursor,
                                              unsigned int* __restrict__ csr4) {
    int e = blockIdx.x * 256 + threadIdx.x;
    if (e >= NE) return;
    int src, dst;
    if (*flag) {
        const long long* p = (const long long*)eidx;
        src = (int)p[e];
        dst = (int)p[NE + e];
    } else {
        const int* p = (const int*)eidx;
        src = p[e];
        dst = p[NE + e];
    }
    int pos = atomicAdd(&cursor[dst], 1);
    unsigned short wb = __half_as_ushort(__float2half(ew[e]));
    csr4[pos] = (unsigned int)(src & 0xFFFF) | ((unsigned int)wb << 16);
}

// ---------------------------------------------------------------------------
// One-shot fp32 -> fp16 conversion of x0 (gather shadow copy).
// ---------------------------------------------------------------------------
__global__ __launch_bounds__(256) void cvt_k(const float* __restrict__ x,
                                             __half* __restrict__ y) {
    int i = blockIdx.x * 256 + threadIdx.x;
    if (i >= NN * DD / 4) return;
    float4 v = ((const float4*)x)[i];
    __half2 a = __floats2half2_rn(v.x, v.y);
    __half2 b = __floats2half2_rn(v.z, v.w);
    ((__half2*)y)[2 * i]     = a;
    ((__half2*)y)[2 * i + 1] = b;
}

// ---------------------------------------------------------------------------
// One-shot: W (fp32 [NL][128][64]) -> fp16 B-fragment order for
// mfma_f32_16x16x32_f16.
// ---------------------------------------------------------------------------
__global__ __launch_bounds__(256) void wfrag_k(const float* __restrict__ W,
                                               __half* __restrict__ Wfrag) {
    int t = blockIdx.x * 256 + threadIdx.x;
    if (t >= NL * 1024) return;
    int l    = t >> 10;
    int kb   = (t >> 8) & 3;
    int nt   = (t >> 6) & 3;
    int lane = t & 63;
    int kg = lane >> 4, n = nt * 16 + (lane & 15);
    const float* Wl = W + (size_t)l * 128 * 64;
    __half* dst = Wfrag + (size_t)t * 8;
    #pragma unroll
    for (int j = 0; j < 8; ++j) {
        int k = kb * 32 + kg * 8 + j;
        dst[j] = __float2half(Wl[k * 64 + n]);
    }
}

// ---------------------------------------------------------------------------
// Fused layer (R9-passed structure, unchanged). 256 threads = 4 waves; each
// wave owns 16 nodes, no barriers.
//   phase 1: 4 gather-quads (8 edge-slots x 8 chunks, fp16 rows, 4B csr),
//            l2norm, normalized aggr (fp16) into XOR-swizzled LDS rows.
//   phase 2: MFMA MLP: D(16x64) = [an | x16](16x128) @ Wfrag via 16x
//            mfma_f32_16x16x32_f16; f32 bias + l2norm epilogue.
// fp16-only chaining; f32 written only on the last layer (d_out).
// ---------------------------------------------------------------------------
__global__ __launch_bounds__(256) void layer_k(const __half* __restrict__ xin16,
                                               const __half* __restrict__ Wfl,
                                               const float* __restrict__ bl,
                                               const int* __restrict__ offs,
                                               const unsigned int* __restrict__ csr4,
                                               __half* __restrict__ xout16,
                                               float* __restrict__ fout,
                                               int writeF32) {
    __shared__ __align__(16) __half an_lds[4 * 16 * 64];  // 8 KB
    int tid = threadIdx.x;
    int wave = tid >> 6, lane = tid & 63;
    int e8 = lane >> 3, c8 = lane & 7;
    int kg = lane >> 4, l15 = lane & 15;
    int nb16 = blockIdx.x * 64 + wave * 16;

    // ---------------- phase 1: gather 4 quads ----------------
    for (int q = 0; q < 4; ++q) {
        int nq = nb16 + q * 4;
        int n0 = min(nq + 0, NN - 1);
        int n1 = min(nq + 1, NN - 1);
        int n2 = min(nq + 2, NN - 1);
        int n3 = min(nq + 3, NN - 1);
        int a0 = offs[n0], a1 = offs[n0 + 1];
        int b0 = offs[n1], b1 = offs[n1 + 1];
        int c0 = offs[n2], c1 = offs[n2 + 1];
        int d0 = offs[n3], d1 = offs[n3 + 1];
        int mx = max(max((a1 - a0 + 7) >> 3, (b1 - b0 + 7) >> 3),
                     max((c1 - c0 + 7) >> 3, (d1 - d0 + 7) >> 3));

        float acc0[8] = {0.f,0.f,0.f,0.f,0.f,0.f,0.f,0.f};
        float acc1[8] = {0.f,0.f,0.f,0.f,0.f,0.f,0.f,0.f};
        float acc2[8] = {0.f,0.f,0.f,0.f,0.f,0.f,0.f,0.f};
        float acc3[8] = {0.f,0.f,0.f,0.f,0.f,0.f,0.f,0.f};

        #pragma unroll 2
        for (int it = 0; it < mx; ++it) {
            int eb = it * 8 + e8;
            int e;
            unsigned int u;
            e = a0 + eb;
            u = csr4[(e < a1) ? e : 0];
            float w0 = (e < a1) ? __half2float(__ushort_as_half((unsigned short)(u >> 16))) : 0.f;
            float4 r0 = *(const float4*)(xin16 + ((size_t)(u & 0xFFFFu) << 6) + (c8 << 3));
            e = b0 + eb;
            u = csr4[(e < b1) ? e : 0];
            float w1 = (e < b1) ? __half2float(__ushort_as_half((unsigned short)(u >> 16))) : 0.f;
            float4 r1 = *(const float4*)(xin16 + ((size_t)(u & 0xFFFFu) << 6) + (c8 << 3));
            e = c0 + eb;
            u = csr4[(e < c1) ? e : 0];
            float w2 = (e < c1) ? __half2float(__ushort_as_half((unsigned short)(u >> 16))) : 0.f;
            float4 r2 = *(const float4*)(xin16 + ((size_t)(u & 0xFFFFu) << 6) + (c8 << 3));
            e = d0 + eb;
            u = csr4[(e < d1) ? e : 0];
            float w3 = (e < d1) ? __half2float(__ushort_as_half((unsigned short)(u >> 16))) : 0.f;
            float4 r3 = *(const float4*)(xin16 + ((size_t)(u & 0xFFFFu) << 6) + (c8 << 3));

            const __half2* h0 = (const __half2*)&r0;
            const __half2* h1 = (const __half2*)&r1;
            const __half2* h2 = (const __half2*)&r2;
            const __half2* h3 = (const __half2*)&r3;
            #pragma unroll
            for (int i = 0; i < 4; ++i) {
                float2 f0 = __half22float2(h0[i]);
                float2 f1 = __half22float2(h1[i]);
                float2 f2 = __half22float2(h2[i]);
                float2 f3 = __half22float2(h3[i]);
                acc0[2*i]   += w0 * f0.x;  acc0[2*i+1] += w0 * f0.y;
                acc1[2*i]   += w1 * f1.x;  acc1[2*i+1] += w1 * f1.y;
                acc2[2*i]   += w2 * f2.x;  acc2[2*i+1] += w2 * f2.y;
                acc3[2*i]   += w3 * f3.x;  acc3[2*i+1] += w3 * f3.y;
            }
        }

        // reduce partial sums across the 8 edge-slots (lane bits 3..5)
        #pragma unroll
        for (int i = 0; i < 8; ++i) {
            acc0[i] += __shfl_xor(acc0[i], 8);
            acc1[i] += __shfl_xor(acc1[i], 8);
            acc2[i] += __shfl_xor(acc2[i], 8);
            acc3[i] += __shfl_xor(acc3[i], 8);
            acc0[i] += __shfl_xor(acc0[i], 16);
            acc1[i] += __shfl_xor(acc1[i], 16);
            acc2[i] += __shfl_xor(acc2[i], 16);
            acc3[i] += __shfl_xor(acc3[i], 16);
            acc0[i] += __shfl_xor(acc0[i], 32);
            acc1[i] += __shfl_xor(acc1[i], 32);
            acc2[i] += __shfl_xor(acc2[i], 32);
            acc3[i] += __shfl_xor(acc3[i], 32);
        }

        // l2 norm per node: per-lane partial then sum across c8 (bits 0..2)
        float s0 = 0.f, s1 = 0.f, s2 = 0.f, s3 = 0.f;
        #pragma unroll
        for (int i = 0; i < 8; ++i) {
            s0 += acc0[i] * acc0[i];
            s1 += acc1[i] * acc1[i];
            s2 += acc2[i] * acc2[i];
            s3 += acc3[i] * acc3[i];
        }
        #pragma unroll
        for (int off = 1; off <= 4; off <<= 1) {
            s0 += __shfl_xor(s0, off);
            s1 += __shfl_xor(s1, off);
            s2 += __shfl_xor(s2, off);
            s3 += __shfl_xor(s3, off);
        }
        float i0 = 1.f / fmaxf(sqrtf(s0), 1e-12f);
        float i1 = 1.f / fmaxf(sqrtf(s1), 1e-12f);
        float i2 = 1.f / fmaxf(sqrtf(s2), 1e-12f);
        float i3 = 1.f / fmaxf(sqrtf(s3), 1e-12f);
        #pragma unroll
        for (int i = 0; i < 8; ++i) {
            acc0[i] *= i0; acc1[i] *= i1; acc2[i] *= i2; acc3[i] *= i3;
        }

        // write quad's normalized aggr to LDS (fp16, XOR-swizzled 16B slots)
        if (e8 < 4) {
            float ts[8];
            #pragma unroll
            for (int i = 0; i < 8; ++i) {
                float v = acc3[i];
                v = (e8 == 2) ? acc2[i] : v;
                v = (e8 == 1) ? acc1[i] : v;
                v = (e8 == 0) ? acc0[i] : v;
                ts[i] = v;
            }
            int row = q * 4 + e8;
            int slot = c8 ^ (row & 7);
            __half2 p0 = __floats2half2_rn(ts[0], ts[1]);
            __half2 p1 = __floats2half2_rn(ts[2], ts[3]);
            __half2 p2 = __floats2half2_rn(ts[4], ts[5]);
            __half2 p3 = __floats2half2_rn(ts[6], ts[7]);
            uint4 pk;
            pk.x = *(unsigned int*)&p0;
            pk.y = *(unsigned int*)&p1;
            pk.z = *(unsigned int*)&p2;
            pk.w = *(unsigned int*)&p3;
            *((uint4*)&an_lds[((wave * 16 + row) << 6) + (slot << 3)]) = pk;
        }
    }

    // ---------------- phase 2: MFMA MLP ----------------
    f32x4 C0 = {0.f,0.f,0.f,0.f};
    f32x4 C1 = {0.f,0.f,0.f,0.f};
    f32x4 C2 = {0.f,0.f,0.f,0.f};
    f32x4 C3 = {0.f,0.f,0.f,0.f};
    int nodeA = min(nb16 + l15, NN - 1);
    #pragma unroll
    for (int kb = 0; kb < 4; ++kb) {
        f16x8 af;
        if (kb < 2) {
            int sl = kb * 4 + kg;
            af = *(const f16x8*)&an_lds[((wave * 16 + l15) << 6) + ((sl ^ (l15 & 7)) << 3)];
        } else {
            af = *(const f16x8*)(xin16 + ((size_t)nodeA << 6) + ((kb - 2) * 32 + kg * 8));
        }
        const __half* wb = Wfl + (size_t)(kb * 4) * 512 + lane * 8;
        f16x8 bf0 = *(const f16x8*)(wb);
        f16x8 bf1 = *(const f16x8*)(wb + 512);
        f16x8 bf2 = *(const f16x8*)(wb + 1024);
        f16x8 bf3 = *(const f16x8*)(wb + 1536);
        C0 = __builtin_amdgcn_mfma_f32_16x16x32_f16(af, bf0, C0, 0, 0, 0);
        C1 = __builtin_amdgcn_mfma_f32_16x16x32_f16(af, bf1, C1, 0, 0, 0);
        C2 = __builtin_amdgcn_mfma_f32_16x16x32_f16(af, bf2, C2, 0, 0, 0);
        C3 = __builtin_amdgcn_mfma_f32_16x16x32_f16(af, bf3, C3, 0, 0, 0);
    }

    // epilogue: bias (f32), l2norm (f32), store fp16 (+f32 on last layer)
    float bn0 = bl[l15], bn1 = bl[16 + l15], bn2 = bl[32 + l15], bn3 = bl[48 + l15];
    #pragma unroll
    for (int r = 0; r < 4; ++r) {
        float v0 = C0[r] + bn0;
        float v1 = C1[r] + bn1;
        float v2 = C2[r] + bn2;
        float v3 = C3[r] + bn3;
        float t = v0 * v0 + v1 * v1 + v2 * v2 + v3 * v3;
        t += __shfl_xor(t, 1);
        t += __shfl_xor(t, 2);
        t += __shfl_xor(t, 4);
        t += __shfl_xor(t, 8);
        float inv = 1.f / fmaxf(sqrtf(t), 1e-12f);
        int node = nb16 + kg * 4 + r;
        if (node < NN) {
            size_t base = ((size_t)node << 6) + l15;
            xout16[base]      = __float2half(v0 * inv);
            xout16[base + 16] = __float2half(v1 * inv);
            xout16[base + 32] = __float2half(v2 * inv);
            xout16[base + 48] = __float2half(v3 * inv);
            if (writeF32) {
                fout[base]      = v0 * inv;
                fout[base + 16] = v1 * inv;
                fout[base + 32] = v2 * inv;
                fout[base + 48] = v3 * inv;
            }
        }
    }
}

// ---------------------------------------------------------------------------
extern "C" void kernel_launch(void* const* d_in, const int* in_sizes, int n_in,
                              void* d_out, int out_size, void* d_ws, size_t ws_size,
                              hipStream_t stream) {
    const float* x0  = (const float*)d_in[0];
    const void*  eidx = d_in[1];
    const float* ew  = (const float*)d_in[2];
    const float* W   = (const float*)d_in[3];
    const float* b   = (const float*)d_in[4];
    float* out = (float*)d_out;

    char* p = (char*)d_ws;
    auto alloc = [&](size_t bytes) {
        char* r = p;
        p += (bytes + 255) & ~(size_t)255;
        return r;
    };
    int*          flag   = (int*)alloc(4);
    int*          cnt    = (int*)alloc((size_t)NN * 4);
    int*          offs   = (int*)alloc((size_t)(NN + 1) * 4);
    int*          cursor = (int*)alloc((size_t)NN * 4);
    int*          psum   = (int*)alloc(64 * 4);
    int*          pbase  = (int*)alloc(64 * 4);
    unsigned int* csr4   = (unsigned int*)alloc((size_t)NE * 4);
    __half*       x16a   = (__half*)alloc((size_t)NN * DD * 2);
    __half*       x16b   = (__half*)alloc((size_t)NN * DD * 2);
    __half*       Wfrag  = (__half*)alloc((size_t)NL * 8192 * 2);

    hipMemsetAsync(cnt, 0, (size_t)NN * 4, stream);
    detect_i64<<<1, 256, 0, stream>>>((const unsigned int*)eidx, flag);
    hist_k<<<(NE + 255) / 256, 256, 0, stream>>>(eidx, flag, cnt);
    part_k<<<NBLK, 256, 0, stream>>>(cnt, psum);
    pscan_k<<<1, 64, 0, stream>>>(psum, pbase, offs);
    offs_k<<<NBLK, 256, 0, stream>>>(cnt, pbase, offs, cursor);
    fill_k<<<(NE + 255) / 256, 256, 0, stream>>>(eidx, ew, flag, cursor, csr4);
    cvt_k<<<(NN * DD / 4 + 255) / 256, 256, 0, stream>>>(x0, x16a);
    wfrag_k<<<(NL * 1024 + 255) / 256, 256, 0, stream>>>(W, Wfrag);

    int nblk = (NN + 63) / 64;   // 64 nodes per 256-thread block
    for (int i = 0; i < NL; ++i) {
        const __half* xi = (i % 2 == 0) ? x16a : x16b;
        __half*       xo = (i % 2 == 0) ? x16b : x16a;
        layer_k<<<nblk, 256, 0, stream>>>(xi, Wfrag + (size_t)i * 8192,
                                          b + (size_t)i * 64, offs, csr4, xo,
                                          out, (i == NL - 1) ? 1 : 0);
    }
}

// Round 12
// 621.445 us; speedup vs baseline: 3.1330x; 1.0258x over previous
//
#include <hip/hip_runtime.h>
#include <hip/hip_fp16.h>

#define NN 50000
#define NE 800000
#define NL 12
#define DD 64
#define NBLK 49   // ceil(50000/1024) blocks of 256 threads x int4

typedef _Float16 f16x8 __attribute__((ext_vector_type(8)));
typedef float f32x4 __attribute__((ext_vector_type(4)));

// ---------------------------------------------------------------------------
// Detect whether edge_index is stored as int64 (odd 32-bit words all zero).
// ---------------------------------------------------------------------------
__global__ __launch_bounds__(256) void detect_i64(const unsigned int* __restrict__ w,
                                                  int* __restrict__ flag) {
    __shared__ unsigned int red[256];
    unsigned int v = 0;
    for (int i = threadIdx.x; i < 4096; i += 256) v |= w[2 * i + 1];
    red[threadIdx.x] = v;
    __syncthreads();
    for (int s = 128; s > 0; s >>= 1) {
        if (threadIdx.x < s) red[threadIdx.x] |= red[threadIdx.x + s];
        __syncthreads();
    }
    if (threadIdx.x == 0) *flag = (red[0] == 0u) ? 1 : 0;
}

__global__ __launch_bounds__(256) void hist_k(const void* __restrict__ eidx,
                                              const int* __restrict__ flag,
                                              int* __restrict__ cnt) {
    int e = blockIdx.x * 256 + threadIdx.x;
    if (e >= NE) return;
    int dst;
    if (*flag) dst = (int)((const long long*)eidx)[NE + e];
    else       dst = ((const int*)eidx)[NE + e];
    atomicAdd(&cnt[dst], 1);
}

// ---------------------------------------------------------------------------
// Multi-block scan, 3 phases.
// ---------------------------------------------------------------------------
__global__ __launch_bounds__(256) void part_k(const int* __restrict__ cnt,
                                              int* __restrict__ psum) {
    __shared__ int wls[4];
    int tid = threadIdx.x, lane = tid & 63, wv = tid >> 6;
    int idx4 = blockIdx.x * 256 + tid;
    int4 c = (idx4 < NN / 4) ? ((const int4*)cnt)[idx4] : make_int4(0, 0, 0, 0);
    int s = c.x + c.y + c.z + c.w;
    #pragma unroll
    for (int off = 32; off > 0; off >>= 1) s += __shfl_xor(s, off);
    if (lane == 0) wls[wv] = s;
    __syncthreads();
    if (tid == 0) psum[blockIdx.x] = wls[0] + wls[1] + wls[2] + wls[3];
}

__global__ __launch_bounds__(64) void pscan_k(const int* __restrict__ psum,
                                              int* __restrict__ pbase,
                                              int* __restrict__ offs) {
    int tid = threadIdx.x;
    int v = (tid < NBLK) ? psum[tid] : 0;
    int incl = v;
    #pragma unroll
    for (int d = 1; d < 64; d <<= 1) {
        int t = __shfl_up(incl, d);
        if (tid >= d) incl += t;
    }
    if (tid < NBLK) pbase[tid] = incl - v;
    if (tid == NBLK - 1) offs[NN] = incl;
}

__global__ __launch_bounds__(256) void offs_k(const int* __restrict__ cnt,
                                              const int* __restrict__ pbase,
                                              int* __restrict__ offs,
                                              int* __restrict__ cursor) {
    __shared__ int wls[4];
    int tid = threadIdx.x, lane = tid & 63, wv = tid >> 6;
    int idx4 = blockIdx.x * 256 + tid;
    int4 c = (idx4 < NN / 4) ? ((const int4*)cnt)[idx4] : make_int4(0, 0, 0, 0);
    int s = c.x + c.y + c.z + c.w;
    int incl = s;
    #pragma unroll
    for (int d = 1; d < 64; d <<= 1) {
        int t = __shfl_up(incl, d);
        if (lane >= d) incl += t;
    }
    if (lane == 63) wls[wv] = incl;
    __syncthreads();
    if (tid == 0) {
        int a = 0;
        #pragma unroll
        for (int j = 0; j < 4; ++j) { int t = wls[j]; wls[j] = a; a += t; }
    }
    __syncthreads();
    int base = pbase[blockIdx.x] + wls[wv] + incl - s;
    int4 o;
    o.x = base;
    o.y = o.x + c.x;
    o.z = o.y + c.y;
    o.w = o.z + c.z;
    if (idx4 < NN / 4) {
        ((int4*)offs)[idx4] = o;
        ((int4*)cursor)[idx4] = o;
    }
}

// ---------------------------------------------------------------------------
// Scatter edges into 4-byte CSR slots: {u16 src, fp16 weight}.
// ---------------------------------------------------------------------------
__global__ __launch_bounds__(256) void fill_k(const void* __restrict__ eidx,
                                              const float* __restrict__ ew,
                                              const int* __restrict__ flag,
                                              int* __restrict__ cursor,
                                              unsigned int* __restrict__ csr4) {
    int e = blockIdx.x * 256 + threadIdx.x;
    if (e >= NE) return;
    int src, dst;
    if (*flag) {
        const long long* p = (const long long*)eidx;
        src = (int)p[e];
        dst = (int)p[NE + e];
    } else {
        const int* p = (const int*)eidx;
        src = p[e];
        dst = p[NE + e];
    }
    int pos = atomicAdd(&cursor[dst], 1);
    unsigned short wb = __half_as_ushort(__float2half(ew[e]));
    csr4[pos] = (unsigned int)(src & 0xFFFF) | ((unsigned int)wb << 16);
}

// ---------------------------------------------------------------------------
// One-shot fp32 -> fp16 conversion of x0 (gather shadow copy).
// ---------------------------------------------------------------------------
__global__ __launch_bounds__(256) void cvt_k(const float* __restrict__ x,
                                             __half* __restrict__ y) {
    int i = blockIdx.x * 256 + threadIdx.x;
    if (i >= NN * DD / 4) return;
    float4 v = ((const float4*)x)[i];
    __half2 a = __floats2half2_rn(v.x, v.y);
    __half2 b = __floats2half2_rn(v.z, v.w);
    ((__half2*)y)[2 * i]     = a;
    ((__half2*)y)[2 * i + 1] = b;
}

// ---------------------------------------------------------------------------
// One-shot: W (fp32 [NL][128][64]) -> fp16 B-fragment order for
// mfma_f32_16x16x32_f16.
// ---------------------------------------------------------------------------
__global__ __launch_bounds__(256) void wfrag_k(const float* __restrict__ W,
                                               __half* __restrict__ Wfrag) {
    int t = blockIdx.x * 256 + threadIdx.x;
    if (t >= NL * 1024) return;
    int l    = t >> 10;
    int kb   = (t >> 8) & 3;
    int nt   = (t >> 6) & 3;
    int lane = t & 63;
    int kg = lane >> 4, n = nt * 16 + (lane & 15);
    const float* Wl = W + (size_t)l * 128 * 64;
    __half* dst = Wfrag + (size_t)t * 8;
    #pragma unroll
    for (int j = 0; j < 8; ++j) {
        int k = kb * 32 + kg * 8 + j;
        dst[j] = __float2half(Wl[k * 64 + n]);
    }
}

// ---------------------------------------------------------------------------
// Fused layer. 256 threads = 4 waves; each wave owns EIGHT nodes (2 quads).
// Occupancy was grid-limited at 12 waves/CU (3125 waves); 8 nodes/wave
// doubles the grid to 6250 waves (~20-24/CU) for gather-latency hiding.
// MFMA keeps M=16 by duplicating A rows (l15&7) — D rows 8..15 are garbage
// and store-masked (kg<2); duplicate rows read identical addresses (no
// extra traffic). Everything else = R11-passed structure.
// ---------------------------------------------------------------------------
__global__ __launch_bounds__(256, 5) void layer_k(const __half* __restrict__ xin16,
                                               const __half* __restrict__ Wfl,
                                               const float* __restrict__ bl,
                                               const int* __restrict__ offs,
                                               const unsigned int* __restrict__ csr4,
                                               __half* __restrict__ xout16,
                                               float* __restrict__ fout,
                                               int writeF32) {
    __shared__ __align__(16) __half an_lds[4 * 8 * 64];  // 4 KB
    int tid = threadIdx.x;
    int wave = tid >> 6, lane = tid & 63;
    int e8 = lane >> 3, c8 = lane & 7;
    int kg = lane >> 4, l15 = lane & 15;
    int nb8 = blockIdx.x * 32 + wave * 8;

    // ---------------- phase 1: gather 2 quads ----------------
    for (int q = 0; q < 2; ++q) {
        int nq = nb8 + q * 4;
        int n0 = min(nq + 0, NN - 1);
        int n1 = min(nq + 1, NN - 1);
        int n2 = min(nq + 2, NN - 1);
        int n3 = min(nq + 3, NN - 1);
        int a0 = offs[n0], a1 = offs[n0 + 1];
        int b0 = offs[n1], b1 = offs[n1 + 1];
        int c0 = offs[n2], c1 = offs[n2 + 1];
        int d0 = offs[n3], d1 = offs[n3 + 1];
        int mx = max(max((a1 - a0 + 7) >> 3, (b1 - b0 + 7) >> 3),
                     max((c1 - c0 + 7) >> 3, (d1 - d0 + 7) >> 3));

        float acc0[8] = {0.f,0.f,0.f,0.f,0.f,0.f,0.f,0.f};
        float acc1[8] = {0.f,0.f,0.f,0.f,0.f,0.f,0.f,0.f};
        float acc2[8] = {0.f,0.f,0.f,0.f,0.f,0.f,0.f,0.f};
        float acc3[8] = {0.f,0.f,0.f,0.f,0.f,0.f,0.f,0.f};

        #pragma unroll 2
        for (int it = 0; it < mx; ++it) {
            int eb = it * 8 + e8;
            int e;
            unsigned int u;
            e = a0 + eb;
            u = csr4[(e < a1) ? e : 0];
            float w0 = (e < a1) ? __half2float(__ushort_as_half((unsigned short)(u >> 16))) : 0.f;
            float4 r0 = *(const float4*)(xin16 + ((size_t)(u & 0xFFFFu) << 6) + (c8 << 3));
            e = b0 + eb;
            u = csr4[(e < b1) ? e : 0];
            float w1 = (e < b1) ? __half2float(__ushort_as_half((unsigned short)(u >> 16))) : 0.f;
            float4 r1 = *(const float4*)(xin16 + ((size_t)(u & 0xFFFFu) << 6) + (c8 << 3));
            e = c0 + eb;
            u = csr4[(e < c1) ? e : 0];
            float w2 = (e < c1) ? __half2float(__ushort_as_half((unsigned short)(u >> 16))) : 0.f;
            float4 r2 = *(const float4*)(xin16 + ((size_t)(u & 0xFFFFu) << 6) + (c8 << 3));
            e = d0 + eb;
            u = csr4[(e < d1) ? e : 0];
            float w3 = (e < d1) ? __half2float(__ushort_as_half((unsigned short)(u >> 16))) : 0.f;
            float4 r3 = *(const float4*)(xin16 + ((size_t)(u & 0xFFFFu) << 6) + (c8 << 3));

            const __half2* h0 = (const __half2*)&r0;
            const __half2* h1 = (const __half2*)&r1;
            const __half2* h2 = (const __half2*)&r2;
            const __half2* h3 = (const __half2*)&r3;
            #pragma unroll
            for (int i = 0; i < 4; ++i) {
                float2 f0 = __half22float2(h0[i]);
                float2 f1 = __half22float2(h1[i]);
                float2 f2 = __half22float2(h2[i]);
                float2 f3 = __half22float2(h3[i]);
                acc0[2*i]   += w0 * f0.x;  acc0[2*i+1] += w0 * f0.y;
                acc1[2*i]   += w1 * f1.x;  acc1[2*i+1] += w1 * f1.y;
                acc2[2*i]   += w2 * f2.x;  acc2[2*i+1] += w2 * f2.y;
                acc3[2*i]   += w3 * f3.x;  acc3[2*i+1] += w3 * f3.y;
            }
        }

        // reduce partial sums across the 8 edge-slots (lane bits 3..5)
        #pragma unroll
        for (int i = 0; i < 8; ++i) {
            acc0[i] += __shfl_xor(acc0[i], 8);
            acc1[i] += __shfl_xor(acc1[i], 8);
            acc2[i] += __shfl_xor(acc2[i], 8);
            acc3[i] += __shfl_xor(acc3[i], 8);
            acc0[i] += __shfl_xor(acc0[i], 16);
            acc1[i] += __shfl_xor(acc1[i], 16);
            acc2[i] += __shfl_xor(acc2[i], 16);
            acc3[i] += __shfl_xor(acc3[i], 16);
            acc0[i] += __shfl_xor(acc0[i], 32);
            acc1[i] += __shfl_xor(acc1[i], 32);
            acc2[i] += __shfl_xor(acc2[i], 32);
            acc3[i] += __shfl_xor(acc3[i], 32);
        }

        // l2 norm per node: per-lane partial then sum across c8 (bits 0..2)
        float s0 = 0.f, s1 = 0.f, s2 = 0.f, s3 = 0.f;
        #pragma unroll
        for (int i = 0; i < 8; ++i) {
            s0 += acc0[i] * acc0[i];
            s1 += acc1[i] * acc1[i];
            s2 += acc2[i] * acc2[i];
            s3 += acc3[i] * acc3[i];
        }
        #pragma unroll
        for (int off = 1; off <= 4; off <<= 1) {
            s0 += __shfl_xor(s0, off);
            s1 += __shfl_xor(s1, off);
            s2 += __shfl_xor(s2, off);
            s3 += __shfl_xor(s3, off);
        }
        float i0 = 1.f / fmaxf(sqrtf(s0), 1e-12f);
        float i1 = 1.f / fmaxf(sqrtf(s1), 1e-12f);
        float i2 = 1.f / fmaxf(sqrtf(s2), 1e-12f);
        float i3 = 1.f / fmaxf(sqrtf(s3), 1e-12f);
        #pragma unroll
        for (int i = 0; i < 8; ++i) {
            acc0[i] *= i0; acc1[i] *= i1; acc2[i] *= i2; acc3[i] *= i3;
        }

        // write quad's normalized aggr to LDS (fp16, XOR-swizzled 16B slots)
        if (e8 < 4) {
            float ts[8];
            #pragma unroll
            for (int i = 0; i < 8; ++i) {
                float v = acc3[i];
                v = (e8 == 2) ? acc2[i] : v;
                v = (e8 == 1) ? acc1[i] : v;
                v = (e8 == 0) ? acc0[i] : v;
                ts[i] = v;
            }
            int row = q * 4 + e8;          // 0..7
            int slot = c8 ^ row;           // row < 8
            __half2 p0 = __floats2half2_rn(ts[0], ts[1]);
            __half2 p1 = __floats2half2_rn(ts[2], ts[3]);
            __half2 p2 = __floats2half2_rn(ts[4], ts[5]);
            __half2 p3 = __floats2half2_rn(ts[6], ts[7]);
            uint4 pk;
            pk.x = *(unsigned int*)&p0;
            pk.y = *(unsigned int*)&p1;
            pk.z = *(unsigned int*)&p2;
            pk.w = *(unsigned int*)&p3;
            *((uint4*)&an_lds[((wave * 8 + row) << 6) + (slot << 3)]) = pk;
        }
    }

    // ---------------- phase 2: MFMA MLP ----------------
    // A rows: l15 0..7 = this wave's 8 nodes; rows 8..15 duplicate (l15&7).
    f32x4 C0 = {0.f,0.f,0.f,0.f};
    f32x4 C1 = {0.f,0.f,0.f,0.f};
    f32x4 C2 = {0.f,0.f,0.f,0.f};
    f32x4 C3 = {0.f,0.f,0.f,0.f};
    int rowA = l15 & 7;
    int nodeA = min(nb8 + rowA, NN - 1);
    #pragma unroll
    for (int kb = 0; kb < 4; ++kb) {
        f16x8 af;
        if (kb < 2) {
            int sl = kb * 4 + kg;
            af = *(const f16x8*)&an_lds[((wave * 8 + rowA) << 6) + ((sl ^ rowA) << 3)];
        } else {
            af = *(const f16x8*)(xin16 + ((size_t)nodeA << 6) + ((kb - 2) * 32 + kg * 8));
        }
        const __half* wb = Wfl + (size_t)(kb * 4) * 512 + lane * 8;
        f16x8 bf0 = *(const f16x8*)(wb);
        f16x8 bf1 = *(const f16x8*)(wb + 512);
        f16x8 bf2 = *(const f16x8*)(wb + 1024);
        f16x8 bf3 = *(const f16x8*)(wb + 1536);
        C0 = __builtin_amdgcn_mfma_f32_16x16x32_f16(af, bf0, C0, 0, 0, 0);
        C1 = __builtin_amdgcn_mfma_f32_16x16x32_f16(af, bf1, C1, 0, 0, 0);
        C2 = __builtin_amdgcn_mfma_f32_16x16x32_f16(af, bf2, C2, 0, 0, 0);
        C3 = __builtin_amdgcn_mfma_f32_16x16x32_f16(af, bf3, C3, 0, 0, 0);
    }

    // epilogue: bias (f32), l2norm (f32), store fp16 (+f32 on last layer).
    // D rows (= kg*4+r) >= 8 are duplicates -> only kg<2 stores.
    float bn0 = bl[l15], bn1 = bl[16 + l15], bn2 = bl[32 + l15], bn3 = bl[48 + l15];
    #pragma unroll
    for (int r = 0; r < 4; ++r) {
        float v0 = C0[r] + bn0;
        float v1 = C1[r] + bn1;
        float v2 = C2[r] + bn2;
        float v3 = C3[r] + bn3;
        float t = v0 * v0 + v1 * v1 + v2 * v2 + v3 * v3;
        t += __shfl_xor(t, 1);
        t += __shfl_xor(t, 2);
        t += __shfl_xor(t, 4);
        t += __shfl_xor(t, 8);
        float inv = 1.f / fmaxf(sqrtf(t), 1e-12f);
        int node = nb8 + kg * 4 + r;
        if (kg < 2 && node < NN) {
            size_t base = ((size_t)node << 6) + l15;
            xout16[base]      = __float2half(v0 * inv);
            xout16[base + 16] = __float2half(v1 * inv);
            xout16[base + 32] = __float2half(v2 * inv);
            xout16[base + 48] = __float2half(v3 * inv);
            if (writeF32) {
                fout[base]      = v0 * inv;
                fout[base + 16] = v1 * inv;
                fout[base + 32] = v2 * inv;
                fout[base + 48] = v3 * inv;
            }
        }
    }
}

// ---------------------------------------------------------------------------
extern "C" void kernel_launch(void* const* d_in, const int* in_sizes, int n_in,
                              void* d_out, int out_size, void* d_ws, size_t ws_size,
                              hipStream_t stream) {
    const float* x0  = (const float*)d_in[0];
    const void*  eidx = d_in[1];
    const float* ew  = (const float*)d_in[2];
    const float* W   = (const float*)d_in[3];
    const float* b   = (const float*)d_in[4];
    float* out = (float*)d_out;

    char* p = (char*)d_ws;
    auto alloc = [&](size_t bytes) {
        char* r = p;
        p += (bytes + 255) & ~(size_t)255;
        return r;
    };
    int*          flag   = (int*)alloc(4);
    int*          cnt    = (int*)alloc((size_t)NN * 4);
    int*          offs   = (int*)alloc((size_t)(NN + 1) * 4);
    int*          cursor = (int*)alloc((size_t)NN * 4);
    int*          psum   = (int*)alloc(64 * 4);
    int*          pbase  = (int*)alloc(64 * 4);
    unsigned int* csr4   = (unsigned int*)alloc((size_t)NE * 4);
    __half*       x16a   = (__half*)alloc((size_t)NN * DD * 2);
    __half*       x16b   = (__half*)alloc((size_t)NN * DD * 2);
    __half*       Wfrag  = (__half*)alloc((size_t)NL * 8192 * 2);

    hipMemsetAsync(cnt, 0, (size_t)NN * 4, stream);
    detect_i64<<<1, 256, 0, stream>>>((const unsigned int*)eidx, flag);
    hist_k<<<(NE + 255) / 256, 256, 0, stream>>>(eidx, flag, cnt);
    part_k<<<NBLK, 256, 0, stream>>>(cnt, psum);
    pscan_k<<<1, 64, 0, stream>>>(psum, pbase, offs);
    offs_k<<<NBLK, 256, 0, stream>>>(cnt, pbase, offs, cursor);
    fill_k<<<(NE + 255) / 256, 256, 0, stream>>>(eidx, ew, flag, cursor, csr4);
    cvt_k<<<(NN * DD / 4 + 255) / 256, 256, 0, stream>>>(x0, x16a);
    wfrag_k<<<(NL * 1024 + 255) / 256, 256, 0, stream>>>(W, Wfrag);

    int nblk = (NN + 31) / 32;   // 32 nodes per 256-thread block (8/wave)
    for (int i = 0; i < NL; ++i) {
        const __half* xi = (i % 2 == 0) ? x16a : x16b;
        __half*       xo = (i % 2 == 0) ? x16b : x16a;
        layer_k<<<nblk, 256, 0, stream>>>(xi, Wfrag + (size_t)i * 8192,
                                          b + (size_t)i * 64, offs, csr4, xo,
                                          out, (i == NL - 1) ? 1 : 0);
    }
}